// Round 1
// baseline (5468.719 us; speedup 1.0000x reference)
//
#include <hip/hip_runtime.h>

#define HF 128
typedef unsigned short ushort_t;
typedef __attribute__((ext_vector_type(8))) short bh8;
typedef __attribute__((ext_vector_type(4))) float f32x4;

__device__ __forceinline__ ushort_t f2bf(float f){
  unsigned u = __float_as_uint(f);
  u += 0x7FFFu + ((u>>16)&1u);
  return (ushort_t)(u>>16);
}
__device__ __forceinline__ bh8 cvt8(f32x4 a, f32x4 b){
  bh8 r;
  r[0]=(short)f2bf(a[0]); r[1]=(short)f2bf(a[1]); r[2]=(short)f2bf(a[2]); r[3]=(short)f2bf(a[3]);
  r[4]=(short)f2bf(b[0]); r[5]=(short)f2bf(b[1]); r[6]=(short)f2bf(b[2]); r[7]=(short)f2bf(b[3]);
  return r;
}
__device__ __forceinline__ float tanh_fast(float x){
  float xc = fminf(fmaxf(x,-15.f),15.f);
  float t = __expf(2.f*xc);
  return __fdividef(t-1.f, t+1.f);
}

// ---------------- prep: zero msgs+counters, build transposed bf16 weights ----
__global__ void prep_kernel(float* __restrict__ msgs, int* __restrict__ cnt,
    const float* __restrict__ nW1, const float* __restrict__ nW2,
    const float* __restrict__ eW1, const float* __restrict__ eW2,
    ushort_t* __restrict__ wt1n, ushort_t* __restrict__ wt2n,
    ushort_t* __restrict__ wt1e, ushort_t* __restrict__ wt2e, int N)
{
  const long T1N = 2l*128*256, T2N = 2l*128*128, T1E = 3l*128*384, T2E = 3l*128*128;
  const long nz = (long)N*HF;
  const long total = nz + 8 + T1N + T2N + T1E + T2E;
  const long stride = (long)gridDim.x*blockDim.x;
  for (long i = (long)blockIdx.x*blockDim.x + threadIdx.x; i < total; i += stride){
    if (i < nz){ msgs[i] = 0.f; }
    else if (i < nz+8){ cnt[i-nz] = 0; }
    else {
      long j = i - nz - 8;
      if (j < T1N){
        long t=j/32768, r=j%32768, n=r/256, k=r%256;
        wt1n[j] = f2bf(nW1[(t*256+k)*128 + n]);
      } else if (j < T1N+T2N){
        long j2=j-T1N, t=j2/16384, r=j2%16384, n=r/128, k=r%128;
        wt2n[j2] = f2bf(nW2[(t*128+k)*128 + n]);
      } else if (j < T1N+T2N+T1E){
        long j2=j-T1N-T2N, t=j2/49152, r=j2%49152, n=r/384, k=r%384;
        wt1e[j2] = f2bf(eW1[(t*384+k)*128 + n]);
      } else {
        long j2=j-T1N-T2N-T1E, t=j2/16384, r=j2%16384, n=r/128, k=r%128;
        wt2e[j2] = f2bf(eW2[(t*128+k)*128 + n]);
      }
    }
  }
}

// ------------- scatter: msgs atomic-add + bucket nodes by type / edges by combo
__global__ void scatter_kernel(const float* __restrict__ e, const int* __restrict__ ei,
    const int* __restrict__ vid, float* __restrict__ msgs, int* __restrict__ cnt,
    int* __restrict__ nlist, int* __restrict__ elist, int N, int E)
{
  const long eh = (long)E*HF;
  const long total = eh + E + N;
  const long stride = (long)gridDim.x*blockDim.x;
  for (long i = (long)blockIdx.x*blockDim.x + threadIdx.x; i < total; i += stride){
    if (i < eh){
      int eidx = (int)(i>>7), h = (int)(i&127);
      int dst = ei[E + eidx];                       // end node
      atomicAdd(&msgs[(size_t)dst*HF + h], e[i]);
    } else if (i < eh + E){
      int j = (int)(i - eh);
      int cmb = vid[ei[j]] + vid[ei[E+j]];
      int pos = atomicAdd(&cnt[2+cmb], 1);
      elist[(size_t)cmb*E + pos] = j;
    } else {
      int j = (int)(i - eh - E);
      int t = vid[j];
      int pos = atomicAdd(&cnt[t], 1);
      nlist[(size_t)t*N + pos] = j;
    }
  }
}

// ---------------- node MLP: [x|msgs] @ W1 -> LN -> relu -> @ W2 -> LN -> tanh -> +x
__global__ __launch_bounds__(256,2) void node_mlp(
    const float* __restrict__ x, const float* __restrict__ msgs,
    const int* __restrict__ nlist, const int* __restrict__ cnt,
    const ushort_t* __restrict__ wt1, const ushort_t* __restrict__ wt2,
    const float* __restrict__ b1, const float* __restrict__ g1, const float* __restrict__ bt1,
    const float* __restrict__ b2, const float* __restrict__ g2, const float* __restrict__ bt2,
    float* __restrict__ out, int N)
{
  const int t = blockIdx.y;
  const int c = cnt[t];
  const int blockbase = blockIdx.x*64;
  if (blockbase >= c) return;
  const int w = threadIdx.x>>6, lane = threadIdx.x&63;
  const int lr = lane&15, lg = lane>>4;
  const int basew = blockbase + (w<<4);
  const int* lst = nlist + (size_t)t*N;
  int pos = basew + lr; if (pos >= c) pos = c-1;
  const int id = lst[pos];

  bh8 a[8];
  #pragma unroll
  for (int kb=0;kb<8;kb++){
    int k0 = kb*32 + lg*8;
    const float* src = (kb<4) ? x + (size_t)id*HF + k0
                              : msgs + (size_t)id*HF + (k0-128);
    f32x4 u0 = *(const f32x4*)src;
    f32x4 u1 = *(const f32x4*)(src+4);
    a[kb] = cvt8(u0,u1);
  }
  const ushort_t* w1t = wt1 + (size_t)t*(128*256);
  f32x4 acc[8];
  #pragma unroll
  for (int ct=0;ct<8;ct++){
    f32x4 z = {0.f,0.f,0.f,0.f}; acc[ct]=z;
    #pragma unroll
    for (int kb=0;kb<8;kb++){
      bh8 b = *(const bh8*)(w1t + (size_t)(ct*16+lr)*256 + kb*32 + lg*8);
      acc[ct] = __builtin_amdgcn_mfma_f32_16x16x32_bf16(a[kb], b, acc[ct], 0,0,0);
    }
  }
  const float* B1 = b1 + t*HF; const float* G1 = g1 + t*HF; const float* BT1 = bt1 + t*HF;
  float s0[4]={0,0,0,0}, q0[4]={0,0,0,0};
  #pragma unroll
  for (int ct=0;ct<8;ct++){
    float bb = B1[(ct<<4)+lr];
    #pragma unroll
    for (int r=0;r<4;r++){ float v=acc[ct][r]+bb; acc[ct][r]=v; s0[r]+=v; q0[r]+=v*v; }
  }
  #pragma unroll
  for (int m=1;m<16;m<<=1){
    #pragma unroll
    for (int r=0;r<4;r++){ s0[r]+=__shfl_xor(s0[r],m); q0[r]+=__shfl_xor(q0[r],m); }
  }
  float mean1[4],rstd1[4];
  #pragma unroll
  for (int r=0;r<4;r++){
    float mu = s0[r]*(1.f/HF);
    float var = q0[r]*(1.f/HF) - mu*mu;
    mean1[r]=mu; rstd1[r]=rsqrtf(var+1e-5f);
  }
  __shared__ ushort_t hbuf[4][2048];   // 16 rows x 128 cols bf16, per wave, swizzled
  ushort_t* hb = hbuf[w];
  #pragma unroll
  for (int ct=0;ct<8;ct++){
    float gg=G1[(ct<<4)+lr], tb=BT1[(ct<<4)+lr];
    #pragma unroll
    for (int r=0;r<4;r++){
      float v = (acc[ct][r]-mean1[r])*rstd1[r]*gg + tb;
      v = fmaxf(v,0.f);
      int row = (lg<<2)+r, col=(ct<<4)+lr;
      int byt = row*256 + col*2; byt ^= (row&7)<<4;
      *(ushort_t*)((char*)hb + byt) = f2bf(v);
    }
  }
  __syncthreads();
  bh8 a2[4];
  #pragma unroll
  for (int kb=0;kb<4;kb++){
    int k0 = kb*32 + lg*8;
    int byt = lr*256 + k0*2; byt ^= (lr&7)<<4;
    a2[kb] = *(const bh8*)((const char*)hb + byt);
  }
  const ushort_t* w2t = wt2 + (size_t)t*(128*128);
  f32x4 acc2[8];
  #pragma unroll
  for (int ct=0;ct<8;ct++){
    f32x4 z = {0.f,0.f,0.f,0.f}; acc2[ct]=z;
    #pragma unroll
    for (int kb=0;kb<4;kb++){
      bh8 b = *(const bh8*)(w2t + (size_t)(ct*16+lr)*128 + kb*32 + lg*8);
      acc2[ct] = __builtin_amdgcn_mfma_f32_16x16x32_bf16(a2[kb], b, acc2[ct], 0,0,0);
    }
  }
  const float* B2 = b2 + t*HF; const float* G2 = g2 + t*HF; const float* BT2 = bt2 + t*HF;
  float s1[4]={0,0,0,0}, q1[4]={0,0,0,0};
  #pragma unroll
  for (int ct=0;ct<8;ct++){
    float bb = B2[(ct<<4)+lr];
    #pragma unroll
    for (int r=0;r<4;r++){ float v=acc2[ct][r]+bb; acc2[ct][r]=v; s1[r]+=v; q1[r]+=v*v; }
  }
  #pragma unroll
  for (int m=1;m<16;m<<=1){
    #pragma unroll
    for (int r=0;r<4;r++){ s1[r]+=__shfl_xor(s1[r],m); q1[r]+=__shfl_xor(q1[r],m); }
  }
  float mean2[4],rstd2[4];
  #pragma unroll
  for (int r=0;r<4;r++){
    float mu = s1[r]*(1.f/HF);
    float var = q1[r]*(1.f/HF) - mu*mu;
    mean2[r]=mu; rstd2[r]=rsqrtf(var+1e-5f);
  }
  int ido[4]; bool pv[4];
  #pragma unroll
  for (int r=0;r<4;r++){
    int pr = basew + (lg<<2) + r;
    pv[r] = pr < c;
    ido[r] = lst[pv[r]? pr : 0];
  }
  #pragma unroll
  for (int ct=0;ct<8;ct++){
    float gg=G2[(ct<<4)+lr], tb=BT2[(ct<<4)+lr];
    #pragma unroll
    for (int r=0;r<4;r++){
      if (pv[r]){
        float v = (acc2[ct][r]-mean2[r])*rstd2[r]*gg + tb;
        v = tanh_fast(v);
        size_t o = (size_t)ido[r]*HF + (ct<<4)+lr;
        out[o] = v + x[o];
      }
    }
  }
}

// ---------------- edge MLP: [xo[s]|xo[d]|e] @ W1 -> LN -> relu -> @ W2 -> LN -> tanh -> +e
__global__ __launch_bounds__(256,2) void edge_mlp(
    const float* __restrict__ xo, const float* __restrict__ e,
    const int* __restrict__ ei,
    const int* __restrict__ elist, const int* __restrict__ cnt,
    const ushort_t* __restrict__ wt1, const ushort_t* __restrict__ wt2,
    const float* __restrict__ b1, const float* __restrict__ g1, const float* __restrict__ bt1,
    const float* __restrict__ b2, const float* __restrict__ g2, const float* __restrict__ bt2,
    float* __restrict__ eout, int E)
{
  const int cc = blockIdx.y;
  const int c = cnt[2+cc];
  const int blockbase = blockIdx.x*64;
  if (blockbase >= c) return;
  const int w = threadIdx.x>>6, lane = threadIdx.x&63;
  const int lr = lane&15, lg = lane>>4;
  const int basew = blockbase + (w<<4);
  const int* lst = elist + (size_t)cc*E;
  int pos = basew + lr; if (pos >= c) pos = c-1;
  const int sedge = lst[pos];
  const int sid = ei[sedge], eid = ei[E+sedge];

  bh8 a[12];
  #pragma unroll
  for (int kb=0;kb<12;kb++){
    int k0 = kb*32 + lg*8;
    const float* src;
    if (kb<4)      src = xo + (size_t)sid*HF + k0;
    else if (kb<8) src = xo + (size_t)eid*HF + (k0-128);
    else           src = e  + (size_t)sedge*HF + (k0-256);
    f32x4 u0 = *(const f32x4*)src;
    f32x4 u1 = *(const f32x4*)(src+4);
    a[kb] = cvt8(u0,u1);
  }
  const ushort_t* w1c = wt1 + (size_t)cc*(128*384);
  f32x4 acc[8];
  #pragma unroll
  for (int ct=0;ct<8;ct++){
    f32x4 z = {0.f,0.f,0.f,0.f}; acc[ct]=z;
    #pragma unroll
    for (int kb=0;kb<12;kb++){
      bh8 b = *(const bh8*)(w1c + (size_t)(ct*16+lr)*384 + kb*32 + lg*8);
      acc[ct] = __builtin_amdgcn_mfma_f32_16x16x32_bf16(a[kb], b, acc[ct], 0,0,0);
    }
  }
  const float* B1 = b1 + cc*HF; const float* G1 = g1 + cc*HF; const float* BT1 = bt1 + cc*HF;
  float s0[4]={0,0,0,0}, q0[4]={0,0,0,0};
  #pragma unroll
  for (int ct=0;ct<8;ct++){
    float bb = B1[(ct<<4)+lr];
    #pragma unroll
    for (int r=0;r<4;r++){ float v=acc[ct][r]+bb; acc[ct][r]=v; s0[r]+=v; q0[r]+=v*v; }
  }
  #pragma unroll
  for (int m=1;m<16;m<<=1){
    #pragma unroll
    for (int r=0;r<4;r++){ s0[r]+=__shfl_xor(s0[r],m); q0[r]+=__shfl_xor(q0[r],m); }
  }
  float mean1[4],rstd1[4];
  #pragma unroll
  for (int r=0;r<4;r++){
    float mu = s0[r]*(1.f/HF);
    float var = q0[r]*(1.f/HF) - mu*mu;
    mean1[r]=mu; rstd1[r]=rsqrtf(var+1e-5f);
  }
  __shared__ ushort_t hbuf[4][2048];
  ushort_t* hb = hbuf[w];
  #pragma unroll
  for (int ct=0;ct<8;ct++){
    float gg=G1[(ct<<4)+lr], tb=BT1[(ct<<4)+lr];
    #pragma unroll
    for (int r=0;r<4;r++){
      float v = (acc[ct][r]-mean1[r])*rstd1[r]*gg + tb;
      v = fmaxf(v,0.f);
      int row = (lg<<2)+r, col=(ct<<4)+lr;
      int byt = row*256 + col*2; byt ^= (row&7)<<4;
      *(ushort_t*)((char*)hb + byt) = f2bf(v);
    }
  }
  __syncthreads();
  bh8 a2[4];
  #pragma unroll
  for (int kb=0;kb<4;kb++){
    int k0 = kb*32 + lg*8;
    int byt = lr*256 + k0*2; byt ^= (lr&7)<<4;
    a2[kb] = *(const bh8*)((const char*)hb + byt);
  }
  const ushort_t* w2c = wt2 + (size_t)cc*(128*128);
  f32x4 acc2[8];
  #pragma unroll
  for (int ct=0;ct<8;ct++){
    f32x4 z = {0.f,0.f,0.f,0.f}; acc2[ct]=z;
    #pragma unroll
    for (int kb=0;kb<4;kb++){
      bh8 b = *(const bh8*)(w2c + (size_t)(ct*16+lr)*128 + kb*32 + lg*8);
      acc2[ct] = __builtin_amdgcn_mfma_f32_16x16x32_bf16(a2[kb], b, acc2[ct], 0,0,0);
    }
  }
  const float* B2 = b2 + cc*HF; const float* G2 = g2 + cc*HF; const float* BT2 = bt2 + cc*HF;
  float s1[4]={0,0,0,0}, q1[4]={0,0,0,0};
  #pragma unroll
  for (int ct=0;ct<8;ct++){
    float bb = B2[(ct<<4)+lr];
    #pragma unroll
    for (int r=0;r<4;r++){ float v=acc2[ct][r]+bb; acc2[ct][r]=v; s1[r]+=v; q1[r]+=v*v; }
  }
  #pragma unroll
  for (int m=1;m<16;m<<=1){
    #pragma unroll
    for (int r=0;r<4;r++){ s1[r]+=__shfl_xor(s1[r],m); q1[r]+=__shfl_xor(q1[r],m); }
  }
  float mean2[4],rstd2[4];
  #pragma unroll
  for (int r=0;r<4;r++){
    float mu = s1[r]*(1.f/HF);
    float var = q1[r]*(1.f/HF) - mu*mu;
    mean2[r]=mu; rstd2[r]=rsqrtf(var+1e-5f);
  }
  int oe[4]; bool pv[4];
  #pragma unroll
  for (int r=0;r<4;r++){
    int pr = basew + (lg<<2) + r;
    pv[r] = pr < c;
    oe[r] = lst[pv[r]? pr : 0];
  }
  #pragma unroll
  for (int ct=0;ct<8;ct++){
    float gg=G2[(ct<<4)+lr], tb=BT2[(ct<<4)+lr];
    #pragma unroll
    for (int r=0;r<4;r++){
      if (pv[r]){
        float v = (acc2[ct][r]-mean2[r])*rstd2[r]*gg + tb;
        v = tanh_fast(v);
        size_t o = (size_t)oe[r]*HF + (ct<<4)+lr;
        eout[o] = v + e[o];
      }
    }
  }
}

extern "C" void kernel_launch(void* const* d_in, const int* in_sizes, int n_in,
                              void* d_out, int out_size, void* d_ws, size_t ws_size,
                              hipStream_t stream)
{
  const float* x   = (const float*)d_in[0];
  const float* e   = (const float*)d_in[1];
  const int*   ei  = (const int*)d_in[2];
  const int*   vid = (const int*)d_in[3];
  const float* nW1 = (const float*)d_in[4];
  const float* nb1 = (const float*)d_in[5];
  const float* ng1 = (const float*)d_in[6];
  const float* nbt1= (const float*)d_in[7];
  const float* nW2 = (const float*)d_in[8];
  const float* nb2 = (const float*)d_in[9];
  const float* ng2 = (const float*)d_in[10];
  const float* nbt2= (const float*)d_in[11];
  const float* eW1 = (const float*)d_in[12];
  const float* eb1 = (const float*)d_in[13];
  const float* eg1 = (const float*)d_in[14];
  const float* ebt1= (const float*)d_in[15];
  const float* eW2 = (const float*)d_in[16];
  const float* eb2 = (const float*)d_in[17];
  const float* eg2 = (const float*)d_in[18];
  const float* ebt2= (const float*)d_in[19];
  const int N = in_sizes[3];
  const int E = in_sizes[2]/2;

  char* p = (char*)d_ws;
  int* cnt   = (int*)p;
  int* nlist = (int*)(p + 256);
  size_t off = 256 + (((size_t)2*N*4 + 255) & ~(size_t)255);
  int* elist = (int*)(p + off);
  off += (((size_t)3*E*4 + 255) & ~(size_t)255);
  ushort_t* wt1n = (ushort_t*)(p + off); off += (size_t)2*128*256*2;
  ushort_t* wt2n = (ushort_t*)(p + off); off += (size_t)2*128*128*2;
  ushort_t* wt1e = (ushort_t*)(p + off); off += (size_t)3*128*384*2;
  ushort_t* wt2e = (ushort_t*)(p + off); off += (size_t)3*128*128*2;

  float* xout = (float*)d_out;
  float* eout = xout + (size_t)N*HF;
  float* msgs = eout;   // e_out region doubles as msgs scratch (written last)

  prep_kernel<<<2048,256,0,stream>>>(msgs,cnt,nW1,nW2,eW1,eW2,wt1n,wt2n,wt1e,wt2e,N);
  scatter_kernel<<<2048,256,0,stream>>>(e,ei,vid,msgs,cnt,nlist,elist,N,E);
  node_mlp<<<dim3((N+63)/64,2),256,0,stream>>>(x,msgs,nlist,cnt,wt1n,wt2n,
      nb1,ng1,nbt1,nb2,ng2,nbt2,xout,N);
  edge_mlp<<<dim3((E+63)/64,3),256,0,stream>>>(xout,e,ei,elist,cnt,wt1e,wt2e,
      eb1,eg1,ebt1,eb2,eg2,ebt2,eout,E);
}